// Round 3
// baseline (2300.643 us; speedup 1.0000x reference)
//
#include <hip/hip_runtime.h>
#include <cstdint>
#include <cstddef>

typedef __bf16 bf16_t;
typedef __bf16 bf16x8 __attribute__((ext_vector_type(8)));
typedef float f32x4 __attribute__((ext_vector_type(4)));

#define B_  4
#define N_  64
#define FP_ 256
#define TP_ 32
#define V_  32000
#define D_  1024
#define L_  2048
#define M_  8192   // B_*L_
#define KCH_ 8000  // GEMM2 K-chunk (fits LLC: 8192*8000*2 = 131 MB + Et 65 MB)
#define CSTRIDE_ 136  // gemm1 LDS epilogue row stride (16B-aligned, bank-spread)

// -------- async global->LDS (16B per lane, wave-uniform LDS base) --------
__device__ __forceinline__ void async_copy16(const void* g, void* l) {
  __builtin_amdgcn_global_load_lds(
      (__attribute__((address_space(1))) void*)g,
      (__attribute__((address_space(3))) void*)l,
      16, 0, 0);
}

__global__ void k_zero(float* __restrict__ p, int n) {
  int i = blockIdx.x * 256 + threadIdx.x;
  if (i < n) p[i] = 0.0f;
}

// -------- x_prime (B,N,FP,TP) fp32 -> Xb (M,FP) bf16, m = b*L + t*N + n --------
__global__ __launch_bounds__(256) void k_convert_x(const float* __restrict__ xp,
                                                   bf16_t* __restrict__ Xb) {
  __shared__ float tile[256][33];
  const int tid = threadIdx.x;
  const int b = blockIdx.x >> 6;
  const int n = blockIdx.x & 63;
  const float* src = xp + (size_t)(b * N_ + n) * FP_ * TP_;
#pragma unroll
  for (int i = 0; i < 32; i++) {
    int idx = i * 256 + tid;
    tile[idx >> 5][idx & 31] = src[idx];
  }
  __syncthreads();
#pragma unroll
  for (int t = 0; t < 32; t++) {
    Xb[(size_t)(b * L_ + t * N_ + n) * FP_ + tid] = (bf16_t)tile[tid][t];
  }
}

// -------- transpose+convert: src (R,C) fp32 -> dst (C,R) bf16 --------
__global__ void k_transpose_cvt(const float* __restrict__ src, bf16_t* __restrict__ dst,
                                int R, int C) {
  __shared__ float tile[64][65];
  int ct = blockIdx.x;
  int rt = blockIdx.y;
  int tid = threadIdx.x;
#pragma unroll
  for (int i = 0; i < 16; i++) {
    int idx = tid + i * 256;
    int a = idx >> 6, bc = idx & 63;
    tile[a][bc] = src[(size_t)(rt * 64 + a) * C + ct * 64 + bc];
  }
  __syncthreads();
#pragma unroll
  for (int i = 0; i < 16; i++) {
    int idx = tid + i * 256;
    int a = idx >> 6, bc = idx & 63;
    dst[(size_t)(ct * 64 + a) * R + rt * 64 + bc] = (bf16_t)tile[bc][a];
  }
}

// ======== GEMM1: P[pr][v] = exp(X[m]·Wt[v] + bias[v]); rowsum[m] += sum_v ========
// Epilogue stages C through LDS -> coalesced dwordx4 stores.
__global__ __launch_bounds__(256) void k_gemm1(
    const bf16_t* __restrict__ Xb, const bf16_t* __restrict__ Wt,
    const float* __restrict__ bias, bf16_t* __restrict__ P,
    float* __restrict__ rowsum, int mbase) {
  __shared__ __align__(16) char smem[128 * CSTRIDE_ * 2];  // 34816 B
  bf16_t* As = (bf16_t*)smem;
  bf16_t* Bs = (bf16_t*)(smem + 16384);
  bf16_t* Cs = (bf16_t*)smem;   // aliases As/Bs after final barrier

  const int tid = threadIdx.x;
  const int lane = tid & 63;
  const int wid = tid >> 6;
  const int wr = wid >> 1, wc = wid & 1;
  const int c16 = lane & 15, quad = lane >> 4;
  const int lrow = lane >> 3;
  const int lchunk = (lane & 7) ^ lrow;

  const int vtile = blockIdx.x;
  const int mtile = blockIdx.y;
  const int m0 = mbase + mtile * 128;
  const int v0 = vtile * 128;

  f32x4 acc[4][4];
#pragma unroll
  for (int i = 0; i < 4; i++)
#pragma unroll
    for (int j = 0; j < 4; j++) acc[i][j] = (f32x4){0.f, 0.f, 0.f, 0.f};

  for (int kt = 0; kt < FP_; kt += 64) {
#pragma unroll
    for (int i = 0; i < 4; i++) {
      int r0 = (wid * 4 + i) * 8;
      int ra = r0 + lrow;
      async_copy16(Xb + (size_t)(m0 + ra) * FP_ + kt + lchunk * 8, &As[r0 * 64]);
      async_copy16(Wt + (size_t)(v0 + ra) * FP_ + kt + lchunk * 8, &Bs[r0 * 64]);
    }
    __syncthreads();
#pragma unroll
    for (int s = 0; s < 2; s++) {
      bf16x8 af[4], bfr[4];
      int g = s * 4 + quad;
#pragma unroll
      for (int i = 0; i < 4; i++) {
        int r = wr * 64 + i * 16 + c16;
        af[i] = *(const bf16x8*)&As[r * 64 + ((g ^ (r & 7)) << 3)];
        int rn = wc * 64 + i * 16 + c16;
        bfr[i] = *(const bf16x8*)&Bs[rn * 64 + ((g ^ (rn & 7)) << 3)];
      }
#pragma unroll
      for (int i = 0; i < 4; i++)
#pragma unroll
        for (int j = 0; j < 4; j++)
          acc[i][j] = __builtin_amdgcn_mfma_f32_16x16x32_bf16(af[i], bfr[j], acc[i][j], 0, 0, 0);
    }
    __syncthreads();   // after final iter: As/Bs free for reuse as Cs
  }

  float bv[4];
#pragma unroll
  for (int j = 0; j < 4; j++) bv[j] = bias[v0 + wc * 64 + j * 16 + c16];

  // exp + rowsum + stage into Cs (local 128x128, stride CSTRIDE_)
#pragma unroll
  for (int i = 0; i < 4; i++) {
#pragma unroll
    for (int e = 0; e < 4; e++) {
      int lr = wr * 64 + i * 16 + quad * 4 + e;  // local row
      int rr = m0 + lr;                          // global row
      float s = 0.0f;
#pragma unroll
      for (int j = 0; j < 4; j++) {
        int lc = wc * 64 + j * 16 + c16;         // local col
        float p = __expf(acc[i][j][e] + bv[j]);
        bf16_t pb = (bf16_t)p;
        Cs[lr * CSTRIDE_ + lc] = pb;
        s += (float)pb;
      }
#pragma unroll
      for (int off = 1; off < 16; off <<= 1) s += __shfl_xor(s, off, 16);
      if (c16 == 0) atomicAdd(&rowsum[rr], s);
    }
  }
  __syncthreads();

  // coalesced store: 8 x bf16x8 per thread
  const int prbase = m0 - mbase;
#pragma unroll
  for (int k = 0; k < 8; k++) {
    int idx = k * 256 + tid;
    int row = idx >> 4, ch = idx & 15;
    *(bf16x8*)&P[(size_t)(prbase + row) * V_ + v0 + ch * 8] =
        *(const bf16x8*)&Cs[row * CSTRIDE_ + ch * 8];
  }
}

// ======== GEMM2 K-chunked: MODE 0=init partial, 1=add, 2=final (+normalize->out) ====
template <int MODE>
__global__ __launch_bounds__(256) void k_gemm2(
    const bf16_t* __restrict__ P, const bf16_t* __restrict__ Et,
    const float* __restrict__ rowsum, float* __restrict__ partial,
    float* __restrict__ out, int mbase, int kbase) {
  __shared__ __align__(16) bf16_t As[128 * 64];
  __shared__ __align__(16) bf16_t Bs[128 * 64];

  const int tid = threadIdx.x;
  const int lane = tid & 63;
  const int wid = tid >> 6;
  const int wr = wid >> 1, wc = wid & 1;
  const int c16 = lane & 15, quad = lane >> 4;
  const int lrow = lane >> 3;
  const int lchunk = (lane & 7) ^ lrow;

  const int dtile = blockIdx.x;               // 0..7
  const int mtile = blockIdx.y;
  const int m0 = mbase + mtile * 128;
  const int prow0 = mtile * 128;
  const int d0 = dtile * 128;

  f32x4 acc[4][4];
#pragma unroll
  for (int i = 0; i < 4; i++)
#pragma unroll
    for (int j = 0; j < 4; j++) acc[i][j] = (f32x4){0.f, 0.f, 0.f, 0.f};

  for (int kt = kbase; kt < kbase + KCH_; kt += 64) {
#pragma unroll
    for (int i = 0; i < 4; i++) {
      int r0 = (wid * 4 + i) * 8;
      int ra = r0 + lrow;
      async_copy16(P + (size_t)(prow0 + ra) * V_ + kt + lchunk * 8, &As[r0 * 64]);
      async_copy16(Et + (size_t)(d0 + ra) * V_ + kt + lchunk * 8, &Bs[r0 * 64]);
    }
    __syncthreads();
#pragma unroll
    for (int s = 0; s < 2; s++) {
      bf16x8 af[4], bfr[4];
      int g = s * 4 + quad;
#pragma unroll
      for (int i = 0; i < 4; i++) {
        int r = wr * 64 + i * 16 + c16;
        af[i] = *(const bf16x8*)&As[r * 64 + ((g ^ (r & 7)) << 3)];
        int rn = wc * 64 + i * 16 + c16;
        bfr[i] = *(const bf16x8*)&Bs[rn * 64 + ((g ^ (rn & 7)) << 3)];
      }
#pragma unroll
      for (int i = 0; i < 4; i++)
#pragma unroll
        for (int j = 0; j < 4; j++)
          acc[i][j] = __builtin_amdgcn_mfma_f32_16x16x32_bf16(af[i], bfr[j], acc[i][j], 0, 0, 0);
    }
    __syncthreads();
  }

#pragma unroll
  for (int i = 0; i < 4; i++) {
#pragma unroll
    for (int e = 0; e < 4; e++) {
      int rr = m0 + wr * 64 + i * 16 + quad * 4 + e;
      float inv = (MODE == 2) ? (1.0f / rowsum[rr]) : 0.0f;
#pragma unroll
      for (int j = 0; j < 4; j++) {
        int d = d0 + wc * 64 + j * 16 + c16;
        size_t off = (size_t)rr * D_ + d;
        if (MODE == 0)
          partial[off] = acc[i][j][e];
        else if (MODE == 1)
          partial[off] += acc[i][j][e];
        else
          out[off] = (partial[off] + acc[i][j][e]) * inv;
      }
    }
  }
}

// ======== host ========
extern "C" void kernel_launch(void* const* d_in, const int* in_sizes, int n_in,
                              void* d_out, int out_size, void* d_ws, size_t ws_size,
                              hipStream_t stream) {
  const float* xp   = (const float*)d_in[0];   // (B,N,FP,TP)
  const float* E    = (const float*)d_in[1];   // (V,D)
  const float* W    = (const float*)d_in[2];   // (FP,V)
  const float* bias = (const float*)d_in[3];   // (V)
  float* out = (float*)d_out;                  // (M,D)

  char* ws = (char*)d_ws;
  const size_t szXb = (size_t)M_ * FP_ * 2;
  const size_t szWt = (size_t)V_ * FP_ * 2;
  const size_t szEt = (size_t)D_ * V_ * 2;
  const size_t szRs = (size_t)M_ * 4;
  const size_t szPart = (size_t)M_ * D_ * 4;
  bf16_t* Xb = (bf16_t*)ws;
  bf16_t* Wt = (bf16_t*)(ws + szXb);
  bf16_t* Et = (bf16_t*)(ws + szXb + szWt);
  float* rowsum = (float*)(ws + szXb + szWt + szEt);
  float* partial = (float*)(ws + szXb + szWt + szEt + szRs);
  bf16_t* P = (bf16_t*)(ws + szXb + szWt + szEt + szRs + szPart);

  const size_t fixed = szXb + szWt + szEt + szRs + szPart;
  size_t avail = (ws_size > fixed) ? (ws_size - fixed) : 0;
  long maxrows = (long)(avail / ((size_t)V_ * 2));
  maxrows = (maxrows / 128) * 128;
  if (maxrows > M_) maxrows = M_;
  if (maxrows < 128) maxrows = 128;
  const int chunk = (int)maxrows;

  k_zero<<<(M_ + 255) / 256, 256, 0, stream>>>(rowsum, M_);
  k_convert_x<<<B_ * N_, 256, 0, stream>>>(xp, Xb);
  {
    dim3 g(V_ / 64, FP_ / 64);
    k_transpose_cvt<<<g, 256, 0, stream>>>(W, Wt, FP_, V_);
  }
  {
    dim3 g(D_ / 64, V_ / 64);
    k_transpose_cvt<<<g, 256, 0, stream>>>(E, Et, V_, D_);
  }

  for (int mb = 0; mb < M_; mb += chunk) {
    int rows = M_ - mb;
    if (rows > chunk) rows = chunk;
    dim3 g1(V_ / 128, rows / 128);
    k_gemm1<<<g1, 256, 0, stream>>>(Xb, Wt, bias, P, rowsum, mb);
    dim3 g2(D_ / 128, rows / 128);
    // 4 sequential K-chunks; active P window (rows x 8000 x 2B) + Et (65MB) fits LLC
    k_gemm2<0><<<g2, 256, 0, stream>>>(P, Et, rowsum, partial, out, mb, 0);
    k_gemm2<1><<<g2, 256, 0, stream>>>(P, Et, rowsum, partial, out, mb, KCH_);
    k_gemm2<1><<<g2, 256, 0, stream>>>(P, Et, rowsum, partial, out, mb, 2 * KCH_);
    k_gemm2<2><<<g2, 256, 0, stream>>>(P, Et, rowsum, partial, out, mb, 3 * KCH_);
  }
}

// Round 4
// 1997.776 us; speedup vs baseline: 1.1516x; 1.1516x over previous
//
#include <hip/hip_runtime.h>
#include <cstdint>
#include <cstddef>

typedef __bf16 bf16_t;
typedef __bf16 bf16x8 __attribute__((ext_vector_type(8)));
typedef float f32x4 __attribute__((ext_vector_type(4)));

#define B_  4
#define N_  64
#define FP_ 256
#define TP_ 32
#define V_  32000
#define D_  1024
#define L_  2048
#define M_  8192   // B_*L_
#define CSTRIDE_ 136  // gemm1 LDS epilogue row stride (16B-aligned, bank-spread)

// -------- async global->LDS (16B per lane, wave-uniform LDS base) --------
__device__ __forceinline__ void async_copy16(const void* g, void* l) {
  __builtin_amdgcn_global_load_lds(
      (__attribute__((address_space(1))) void*)g,
      (__attribute__((address_space(3))) void*)l,
      16, 0, 0);
}

__global__ void k_zero(float* __restrict__ p, int n) {
  int i = blockIdx.x * 256 + threadIdx.x;
  if (i < n) p[i] = 0.0f;
}

// -------- x_prime (B,N,FP,TP) fp32 -> Xb (M,FP) bf16, m = b*L + t*N + n --------
__global__ __launch_bounds__(256) void k_convert_x(const float* __restrict__ xp,
                                                   bf16_t* __restrict__ Xb) {
  __shared__ float tile[256][33];
  const int tid = threadIdx.x;
  const int b = blockIdx.x >> 6;
  const int n = blockIdx.x & 63;
  const float* src = xp + (size_t)(b * N_ + n) * FP_ * TP_;
#pragma unroll
  for (int i = 0; i < 32; i++) {
    int idx = i * 256 + tid;
    tile[idx >> 5][idx & 31] = src[idx];
  }
  __syncthreads();
#pragma unroll
  for (int t = 0; t < 32; t++) {
    Xb[(size_t)(b * L_ + t * N_ + n) * FP_ + tid] = (bf16_t)tile[tid][t];
  }
}

// -------- transpose+convert: src (R,C) fp32 -> dst (C,R) bf16 --------
__global__ void k_transpose_cvt(const float* __restrict__ src, bf16_t* __restrict__ dst,
                                int R, int C) {
  __shared__ float tile[64][65];
  int ct = blockIdx.x;
  int rt = blockIdx.y;
  int tid = threadIdx.x;
#pragma unroll
  for (int i = 0; i < 16; i++) {
    int idx = tid + i * 256;
    int a = idx >> 6, bc = idx & 63;
    tile[a][bc] = src[(size_t)(rt * 64 + a) * C + ct * 64 + bc];
  }
  __syncthreads();
#pragma unroll
  for (int i = 0; i < 16; i++) {
    int idx = tid + i * 256;
    int a = idx >> 6, bc = idx & 63;
    dst[(size_t)(ct * 64 + a) * R + rt * 64 + bc] = (bf16_t)tile[bc][a];
  }
}

// ======== GEMM1: P[pr][v] = exp(X[m]·Wt[v] + bias[v]); rowsum[m] += sum_v ========
// K=256 done as 2 barrier-batches of 2x BK=64 (4 LDS buffers, 64 KB) to halve
// the vmcnt(0) barrier drains. Epilogue stages C through LDS -> dwordx4 stores.
// grid: (x=mtile 64, y=vtile 250) -> XCD = mtile%8 (Xb rows XCD-local).
__global__ __launch_bounds__(256) void k_gemm1(
    const bf16_t* __restrict__ Xb, const bf16_t* __restrict__ Wt,
    const float* __restrict__ bias, bf16_t* __restrict__ P,
    float* __restrict__ rowsum, int mbase) {
  __shared__ __align__(16) char smem[65536];
  bf16_t* As[2] = {(bf16_t*)smem, (bf16_t*)(smem + 32768)};
  bf16_t* Bs[2] = {(bf16_t*)(smem + 16384), (bf16_t*)(smem + 49152)};
  bf16_t* Cs = (bf16_t*)smem;   // 34816 B, aliases after final barrier

  const int tid = threadIdx.x;
  const int lane = tid & 63;
  const int wid = tid >> 6;
  const int wr = wid >> 1, wc = wid & 1;
  const int c16 = lane & 15, quad = lane >> 4;
  const int lrow = lane >> 3;
  const int lchunk = (lane & 7) ^ lrow;

  const int mtile = blockIdx.x;
  const int vtile = blockIdx.y;
  const int m0 = mbase + mtile * 128;
  const int v0 = vtile * 128;

  f32x4 acc[4][4];
#pragma unroll
  for (int i = 0; i < 4; i++)
#pragma unroll
    for (int j = 0; j < 4; j++) acc[i][j] = (f32x4){0.f, 0.f, 0.f, 0.f};

#pragma unroll
  for (int kt = 0; kt < FP_; kt += 128) {
#pragma unroll
    for (int i = 0; i < 4; i++) {
      int r0 = (wid * 4 + i) * 8;
      int ra = r0 + lrow;
      const bf16_t* xrow = Xb + (size_t)(m0 + ra) * FP_ + kt + lchunk * 8;
      const bf16_t* wrow = Wt + (size_t)(v0 + ra) * FP_ + kt + lchunk * 8;
      async_copy16(xrow,      &As[0][r0 * 64]);
      async_copy16(xrow + 64, &As[1][r0 * 64]);
      async_copy16(wrow,      &Bs[0][r0 * 64]);
      async_copy16(wrow + 64, &Bs[1][r0 * 64]);
    }
    __syncthreads();
#pragma unroll
    for (int h = 0; h < 2; h++) {
#pragma unroll
      for (int s = 0; s < 2; s++) {
        bf16x8 af[4], bfr[4];
        int g = s * 4 + quad;
#pragma unroll
        for (int i = 0; i < 4; i++) {
          int r = wr * 64 + i * 16 + c16;
          af[i] = *(const bf16x8*)&As[h][r * 64 + ((g ^ (r & 7)) << 3)];
          int rn = wc * 64 + i * 16 + c16;
          bfr[i] = *(const bf16x8*)&Bs[h][rn * 64 + ((g ^ (rn & 7)) << 3)];
        }
#pragma unroll
        for (int i = 0; i < 4; i++)
#pragma unroll
          for (int j = 0; j < 4; j++)
            acc[i][j] = __builtin_amdgcn_mfma_f32_16x16x32_bf16(af[i], bfr[j], acc[i][j], 0, 0, 0);
      }
    }
    __syncthreads();
  }

  float bv[4];
#pragma unroll
  for (int j = 0; j < 4; j++) bv[j] = bias[v0 + wc * 64 + j * 16 + c16];

#pragma unroll
  for (int i = 0; i < 4; i++) {
#pragma unroll
    for (int e = 0; e < 4; e++) {
      int lr = wr * 64 + i * 16 + quad * 4 + e;
      int rr = m0 + lr;
      float s = 0.0f;
#pragma unroll
      for (int j = 0; j < 4; j++) {
        int lc = wc * 64 + j * 16 + c16;
        float p = __expf(acc[i][j][e] + bv[j]);
        bf16_t pb = (bf16_t)p;
        Cs[lr * CSTRIDE_ + lc] = pb;
        s += (float)pb;
      }
#pragma unroll
      for (int off = 1; off < 16; off <<= 1) s += __shfl_xor(s, off, 16);
      if (c16 == 0) atomicAdd(&rowsum[rr], s);
    }
  }
  __syncthreads();

  const int prbase = m0 - mbase;
#pragma unroll
  for (int k = 0; k < 8; k++) {
    int idx = k * 256 + tid;
    int row = idx >> 4, ch = idx & 15;
    *(bf16x8*)&P[(size_t)(prbase + row) * V_ + v0 + ch * 8] =
        *(const bf16x8*)&Cs[row * CSTRIDE_ + ch * 8];
  }
}

// ======== GEMM2: out[m][d] = (sum_v P[pr][v]*Et[d][v]) / rowsum[m] ========
// grid: (x=mtile 64, y=dtile 8) -> XCD = (mtile + 64*dtile)%8 = mtile%8:
// all 8 d-tiles of one m-tile on ONE XCD -> P L2-missed once, re-served by L2.
__global__ __launch_bounds__(256) void k_gemm2(
    const bf16_t* __restrict__ P, const bf16_t* __restrict__ Et,
    const float* __restrict__ rowsum, float* __restrict__ out, int mbase) {
  __shared__ __align__(16) bf16_t As[128 * 64];
  __shared__ __align__(16) bf16_t Bs[128 * 64];

  const int tid = threadIdx.x;
  const int lane = tid & 63;
  const int wid = tid >> 6;
  const int wr = wid >> 1, wc = wid & 1;
  const int c16 = lane & 15, quad = lane >> 4;
  const int lrow = lane >> 3;
  const int lchunk = (lane & 7) ^ lrow;

  const int mtile = blockIdx.x;
  const int dtile = blockIdx.y;
  const int m0 = mbase + mtile * 128;
  const int prow0 = mtile * 128;
  const int d0 = dtile * 128;

  f32x4 acc[4][4];
#pragma unroll
  for (int i = 0; i < 4; i++)
#pragma unroll
    for (int j = 0; j < 4; j++) acc[i][j] = (f32x4){0.f, 0.f, 0.f, 0.f};

  for (int kt = 0; kt < V_; kt += 64) {
#pragma unroll
    for (int i = 0; i < 4; i++) {
      int r0 = (wid * 4 + i) * 8;
      int ra = r0 + lrow;
      async_copy16(P + (size_t)(prow0 + ra) * V_ + kt + lchunk * 8, &As[r0 * 64]);
      async_copy16(Et + (size_t)(d0 + ra) * V_ + kt + lchunk * 8, &Bs[r0 * 64]);
    }
    __syncthreads();
#pragma unroll
    for (int s = 0; s < 2; s++) {
      bf16x8 af[4], bfr[4];
      int g = s * 4 + quad;
#pragma unroll
      for (int i = 0; i < 4; i++) {
        int r = wr * 64 + i * 16 + c16;
        af[i] = *(const bf16x8*)&As[r * 64 + ((g ^ (r & 7)) << 3)];
        int rn = wc * 64 + i * 16 + c16;
        bfr[i] = *(const bf16x8*)&Bs[rn * 64 + ((g ^ (rn & 7)) << 3)];
      }
#pragma unroll
      for (int i = 0; i < 4; i++)
#pragma unroll
        for (int j = 0; j < 4; j++)
          acc[i][j] = __builtin_amdgcn_mfma_f32_16x16x32_bf16(af[i], bfr[j], acc[i][j], 0, 0, 0);
    }
    __syncthreads();
  }

#pragma unroll
  for (int i = 0; i < 4; i++) {
#pragma unroll
    for (int e = 0; e < 4; e++) {
      int rr = m0 + wr * 64 + i * 16 + quad * 4 + e;
      float inv = 1.0f / rowsum[rr];
#pragma unroll
      for (int j = 0; j < 4; j++) {
        int d = d0 + wc * 64 + j * 16 + c16;
        out[(size_t)rr * D_ + d] = acc[i][j][e] * inv;
      }
    }
  }
}

// ======== host ========
extern "C" void kernel_launch(void* const* d_in, const int* in_sizes, int n_in,
                              void* d_out, int out_size, void* d_ws, size_t ws_size,
                              hipStream_t stream) {
  const float* xp   = (const float*)d_in[0];   // (B,N,FP,TP)
  const float* E    = (const float*)d_in[1];   // (V,D)
  const float* W    = (const float*)d_in[2];   // (FP,V)
  const float* bias = (const float*)d_in[3];   // (V)
  float* out = (float*)d_out;                  // (M,D)

  char* ws = (char*)d_ws;
  const size_t szXb = (size_t)M_ * FP_ * 2;
  const size_t szWt = (size_t)V_ * FP_ * 2;
  const size_t szEt = (size_t)D_ * V_ * 2;
  const size_t szRs = (size_t)M_ * 4;
  bf16_t* Xb = (bf16_t*)ws;
  bf16_t* Wt = (bf16_t*)(ws + szXb);
  bf16_t* Et = (bf16_t*)(ws + szXb + szWt);
  float* rowsum = (float*)(ws + szXb + szWt + szEt);
  bf16_t* P = (bf16_t*)(ws + szXb + szWt + szEt + szRs);

  const size_t fixed = szXb + szWt + szEt + szRs;
  size_t avail = (ws_size > fixed) ? (ws_size - fixed) : 0;
  long maxrows = (long)(avail / ((size_t)V_ * 2));
  maxrows = (maxrows / 128) * 128;
  if (maxrows > M_) maxrows = M_;
  if (maxrows < 128) maxrows = 128;
  const int chunk = (int)maxrows;

  k_zero<<<(M_ + 255) / 256, 256, 0, stream>>>(rowsum, M_);
  k_convert_x<<<B_ * N_, 256, 0, stream>>>(xp, Xb);
  {
    dim3 g(V_ / 64, FP_ / 64);
    k_transpose_cvt<<<g, 256, 0, stream>>>(W, Wt, FP_, V_);
  }
  {
    dim3 g(D_ / 64, V_ / 64);
    k_transpose_cvt<<<g, 256, 0, stream>>>(E, Et, V_, D_);
  }

  for (int mb = 0; mb < M_; mb += chunk) {
    int rows = M_ - mb;
    if (rows > chunk) rows = chunk;
    dim3 g1(rows / 128, V_ / 128);   // x=mtile, y=vtile
    k_gemm1<<<g1, 256, 0, stream>>>(Xb, Wt, bias, P, rowsum, mb);
    dim3 g2(rows / 128, D_ / 128);   // x=mtile, y=dtile
    k_gemm2<<<g2, 256, 0, stream>>>(P, Et, rowsum, out, mb);
  }
}

// Round 5
// 1971.738 us; speedup vs baseline: 1.1668x; 1.0132x over previous
//
#include <hip/hip_runtime.h>
#include <cstdint>
#include <cstddef>

typedef __bf16 bf16_t;
typedef __bf16 bf16x8 __attribute__((ext_vector_type(8)));
typedef float f32x4 __attribute__((ext_vector_type(4)));

#define B_  4
#define N_  64
#define FP_ 256
#define TP_ 32
#define V_  32000
#define D_  1024
#define L_  2048
#define M_  8192   // B_*L_
#define CSTRIDE_ 136  // gemm1 LDS epilogue row stride (16B-aligned, bank-spread)

// -------- async global->LDS (16B per lane, wave-uniform LDS base) --------
__device__ __forceinline__ void async_copy16(const void* g, void* l) {
  __builtin_amdgcn_global_load_lds(
      (__attribute__((address_space(1))) void*)g,
      (__attribute__((address_space(3))) void*)l,
      16, 0, 0);
}

__global__ void k_zero(float* __restrict__ p, int n) {
  int i = blockIdx.x * 256 + threadIdx.x;
  if (i < n) p[i] = 0.0f;
}

// -------- x_prime (B,N,FP,TP) fp32 -> Xb (M,FP) bf16, m = b*L + t*N + n --------
__global__ __launch_bounds__(256) void k_convert_x(const float* __restrict__ xp,
                                                   bf16_t* __restrict__ Xb) {
  __shared__ float tile[256][33];
  const int tid = threadIdx.x;
  const int b = blockIdx.x >> 6;
  const int n = blockIdx.x & 63;
  const float* src = xp + (size_t)(b * N_ + n) * FP_ * TP_;
#pragma unroll
  for (int i = 0; i < 32; i++) {
    int idx = i * 256 + tid;
    tile[idx >> 5][idx & 31] = src[idx];
  }
  __syncthreads();
#pragma unroll
  for (int t = 0; t < 32; t++) {
    Xb[(size_t)(b * L_ + t * N_ + n) * FP_ + tid] = (bf16_t)tile[tid][t];
  }
}

// -------- transpose+convert: src (R,C) fp32 -> dst (C,R) bf16 --------
__global__ void k_transpose_cvt(const float* __restrict__ src, bf16_t* __restrict__ dst,
                                int R, int C) {
  __shared__ float tile[64][65];
  int ct = blockIdx.x;
  int rt = blockIdx.y;
  int tid = threadIdx.x;
#pragma unroll
  for (int i = 0; i < 16; i++) {
    int idx = tid + i * 256;
    int a = idx >> 6, bc = idx & 63;
    tile[a][bc] = src[(size_t)(rt * 64 + a) * C + ct * 64 + bc];
  }
  __syncthreads();
#pragma unroll
  for (int i = 0; i < 16; i++) {
    int idx = tid + i * 256;
    int a = idx >> 6, bc = idx & 63;
    dst[(size_t)(ct * 64 + a) * R + rt * 64 + bc] = (bf16_t)tile[bc][a];
  }
}

// ======== GEMM1 (round-3 version, 34.8KB LDS -> 4 blocks/CU): ========
// P[pr][v] = exp(X[m]·Wt[v] + bias[v]); rowsum[m] += sum_v
__global__ __launch_bounds__(256) void k_gemm1(
    const bf16_t* __restrict__ Xb, const bf16_t* __restrict__ Wt,
    const float* __restrict__ bias, bf16_t* __restrict__ P,
    float* __restrict__ rowsum, int mbase) {
  __shared__ __align__(16) char smem[128 * CSTRIDE_ * 2];  // 34816 B
  bf16_t* As = (bf16_t*)smem;
  bf16_t* Bs = (bf16_t*)(smem + 16384);
  bf16_t* Cs = (bf16_t*)smem;   // aliases As/Bs after final barrier

  const int tid = threadIdx.x;
  const int lane = tid & 63;
  const int wid = tid >> 6;
  const int wr = wid >> 1, wc = wid & 1;
  const int c16 = lane & 15, quad = lane >> 4;
  const int lrow = lane >> 3;
  const int lchunk = (lane & 7) ^ lrow;

  const int vtile = blockIdx.x;
  const int mtile = blockIdx.y;
  const int m0 = mbase + mtile * 128;
  const int v0 = vtile * 128;

  f32x4 acc[4][4];
#pragma unroll
  for (int i = 0; i < 4; i++)
#pragma unroll
    for (int j = 0; j < 4; j++) acc[i][j] = (f32x4){0.f, 0.f, 0.f, 0.f};

  for (int kt = 0; kt < FP_; kt += 64) {
#pragma unroll
    for (int i = 0; i < 4; i++) {
      int r0 = (wid * 4 + i) * 8;
      int ra = r0 + lrow;
      async_copy16(Xb + (size_t)(m0 + ra) * FP_ + kt + lchunk * 8, &As[r0 * 64]);
      async_copy16(Wt + (size_t)(v0 + ra) * FP_ + kt + lchunk * 8, &Bs[r0 * 64]);
    }
    __syncthreads();
#pragma unroll
    for (int s = 0; s < 2; s++) {
      bf16x8 af[4], bfr[4];
      int g = s * 4 + quad;
#pragma unroll
      for (int i = 0; i < 4; i++) {
        int r = wr * 64 + i * 16 + c16;
        af[i] = *(const bf16x8*)&As[r * 64 + ((g ^ (r & 7)) << 3)];
        int rn = wc * 64 + i * 16 + c16;
        bfr[i] = *(const bf16x8*)&Bs[rn * 64 + ((g ^ (rn & 7)) << 3)];
      }
#pragma unroll
      for (int i = 0; i < 4; i++)
#pragma unroll
        for (int j = 0; j < 4; j++)
          acc[i][j] = __builtin_amdgcn_mfma_f32_16x16x32_bf16(af[i], bfr[j], acc[i][j], 0, 0, 0);
    }
    __syncthreads();   // after final iter: As/Bs free for reuse as Cs
  }

  float bv[4];
#pragma unroll
  for (int j = 0; j < 4; j++) bv[j] = bias[v0 + wc * 64 + j * 16 + c16];

#pragma unroll
  for (int i = 0; i < 4; i++) {
#pragma unroll
    for (int e = 0; e < 4; e++) {
      int lr = wr * 64 + i * 16 + quad * 4 + e;
      int rr = m0 + lr;
      float s = 0.0f;
#pragma unroll
      for (int j = 0; j < 4; j++) {
        int lc = wc * 64 + j * 16 + c16;
        float p = __expf(acc[i][j][e] + bv[j]);
        bf16_t pb = (bf16_t)p;
        Cs[lr * CSTRIDE_ + lc] = pb;
        s += (float)pb;
      }
#pragma unroll
      for (int off = 1; off < 16; off <<= 1) s += __shfl_xor(s, off, 16);
      if (c16 == 0) atomicAdd(&rowsum[rr], s);
    }
  }
  __syncthreads();

  const int prbase = m0 - mbase;
#pragma unroll
  for (int k = 0; k < 8; k++) {
    int idx = k * 256 + tid;
    int row = idx >> 4, ch = idx & 15;
    *(bf16x8*)&P[(size_t)(prbase + row) * V_ + v0 + ch * 8] =
        *(const bf16x8*)&Cs[row * CSTRIDE_ + ch * 8];
  }
}

// ======== GEMM2: out[m][d] = (sum_v P[pr][v]*Et[d][v]) / rowsum[m] ========
// BK=128 batched: 4x16KB LDS buffers (64KB), one barrier per 128 K-elems
// (250 drains instead of 500; grid already limits to 2 blocks/CU so the
// larger LDS costs no occupancy). grid: (x=mtile, y=dtile).
__global__ __launch_bounds__(256) void k_gemm2(
    const bf16_t* __restrict__ P, const bf16_t* __restrict__ Et,
    const float* __restrict__ rowsum, float* __restrict__ out, int mbase) {
  __shared__ __align__(16) char smem[65536];
  bf16_t* As[2] = {(bf16_t*)smem, (bf16_t*)(smem + 32768)};
  bf16_t* Bs[2] = {(bf16_t*)(smem + 16384), (bf16_t*)(smem + 49152)};

  const int tid = threadIdx.x;
  const int lane = tid & 63;
  const int wid = tid >> 6;
  const int wr = wid >> 1, wc = wid & 1;
  const int c16 = lane & 15, quad = lane >> 4;
  const int lrow = lane >> 3;
  const int lchunk = (lane & 7) ^ lrow;

  const int mtile = blockIdx.x;
  const int dtile = blockIdx.y;
  const int m0 = mbase + mtile * 128;
  const int prow0 = mtile * 128;
  const int d0 = dtile * 128;

  f32x4 acc[4][4];
#pragma unroll
  for (int i = 0; i < 4; i++)
#pragma unroll
    for (int j = 0; j < 4; j++) acc[i][j] = (f32x4){0.f, 0.f, 0.f, 0.f};

  for (int kt = 0; kt < V_; kt += 128) {
#pragma unroll
    for (int i = 0; i < 4; i++) {
      int r0 = (wid * 4 + i) * 8;
      int ra = r0 + lrow;
      const bf16_t* prow = P + (size_t)(prow0 + ra) * V_ + kt + lchunk * 8;
      const bf16_t* erow = Et + (size_t)(d0 + ra) * V_ + kt + lchunk * 8;
      async_copy16(prow,      &As[0][r0 * 64]);
      async_copy16(prow + 64, &As[1][r0 * 64]);
      async_copy16(erow,      &Bs[0][r0 * 64]);
      async_copy16(erow + 64, &Bs[1][r0 * 64]);
    }
    __syncthreads();
#pragma unroll
    for (int h = 0; h < 2; h++) {
#pragma unroll
      for (int s = 0; s < 2; s++) {
        bf16x8 af[4], bfr[4];
        int g = s * 4 + quad;
#pragma unroll
        for (int i = 0; i < 4; i++) {
          int r = wr * 64 + i * 16 + c16;
          af[i] = *(const bf16x8*)&As[h][r * 64 + ((g ^ (r & 7)) << 3)];
          int rn = wc * 64 + i * 16 + c16;
          bfr[i] = *(const bf16x8*)&Bs[h][rn * 64 + ((g ^ (rn & 7)) << 3)];
        }
#pragma unroll
        for (int i = 0; i < 4; i++)
#pragma unroll
          for (int j = 0; j < 4; j++)
            acc[i][j] = __builtin_amdgcn_mfma_f32_16x16x32_bf16(af[i], bfr[j], acc[i][j], 0, 0, 0);
      }
    }
    __syncthreads();
  }

#pragma unroll
  for (int i = 0; i < 4; i++) {
#pragma unroll
    for (int e = 0; e < 4; e++) {
      int rr = m0 + wr * 64 + i * 16 + quad * 4 + e;
      float inv = 1.0f / rowsum[rr];
#pragma unroll
      for (int j = 0; j < 4; j++) {
        int d = d0 + wc * 64 + j * 16 + c16;
        out[(size_t)rr * D_ + d] = acc[i][j][e] * inv;
      }
    }
  }
}

// ======== host ========
extern "C" void kernel_launch(void* const* d_in, const int* in_sizes, int n_in,
                              void* d_out, int out_size, void* d_ws, size_t ws_size,
                              hipStream_t stream) {
  const float* xp   = (const float*)d_in[0];   // (B,N,FP,TP)
  const float* E    = (const float*)d_in[1];   // (V,D)
  const float* W    = (const float*)d_in[2];   // (FP,V)
  const float* bias = (const float*)d_in[3];   // (V)
  float* out = (float*)d_out;                  // (M,D)

  char* ws = (char*)d_ws;
  const size_t szXb = (size_t)M_ * FP_ * 2;
  const size_t szWt = (size_t)V_ * FP_ * 2;
  const size_t szEt = (size_t)D_ * V_ * 2;
  const size_t szRs = (size_t)M_ * 4;
  bf16_t* Xb = (bf16_t*)ws;
  bf16_t* Wt = (bf16_t*)(ws + szXb);
  bf16_t* Et = (bf16_t*)(ws + szXb + szWt);
  float* rowsum = (float*)(ws + szXb + szWt + szEt);
  bf16_t* P = (bf16_t*)(ws + szXb + szWt + szEt + szRs);

  const size_t fixed = szXb + szWt + szEt + szRs;
  size_t avail = (ws_size > fixed) ? (ws_size - fixed) : 0;
  long maxrows = (long)(avail / ((size_t)V_ * 2));
  maxrows = (maxrows / 128) * 128;
  if (maxrows > M_) maxrows = M_;
  if (maxrows < 128) maxrows = 128;
  const int chunk = (int)maxrows;

  k_zero<<<(M_ + 255) / 256, 256, 0, stream>>>(rowsum, M_);
  k_convert_x<<<B_ * N_, 256, 0, stream>>>(xp, Xb);
  {
    dim3 g(V_ / 64, FP_ / 64);
    k_transpose_cvt<<<g, 256, 0, stream>>>(W, Wt, FP_, V_);
  }
  {
    dim3 g(D_ / 64, V_ / 64);
    k_transpose_cvt<<<g, 256, 0, stream>>>(E, Et, V_, D_);
  }

  for (int mb = 0; mb < M_; mb += chunk) {
    int rows = M_ - mb;
    if (rows > chunk) rows = chunk;
    dim3 g1(V_ / 128, rows / 128);   // x=vtile, y=mtile (round-3 proven)
    k_gemm1<<<g1, 256, 0, stream>>>(Xb, Wt, bias, P, rowsum, mb);
    dim3 g2(rows / 128, D_ / 128);   // x=mtile, y=dtile
    k_gemm2<<<g2, 256, 0, stream>>>(P, Et, rowsum, out, mb);
  }
}